// Round 1
// 1551.604 us; speedup vs baseline: 1.0193x; 1.0193x over previous
//
#include <hip/hip_runtime.h>
#include <stdint.h>
#include <stddef.h>

typedef unsigned short u16;
typedef float f32x4 __attribute__((ext_vector_type(4)));
typedef __bf16 bf16x8 __attribute__((ext_vector_type(8)));

#define NNODES 16384
#define HDIM   256
#define MAXD   128
#define BNEPS  1e-5f

__device__ __forceinline__ float bf2f(u16 u) {
  union { uint32_t u; float f; } w; w.u = ((uint32_t)u) << 16; return w.f;
}
__device__ __forceinline__ u16 f2bf(float f) {
  union { float f; uint32_t u; } w; w.f = f;
  return (u16)((w.u + 0x7FFFu + ((w.u >> 16) & 1u)) >> 16);  // RNE
}

union FragB { uint4 q; bf16x8 v; u16 us[8]; };

// ---------------------------------------------------------------------------
// K0 (fused): blocks [0,896) do init work (zero BN-stat shadows + transpose+
// bf16-cast the 4 weight matrices); blocks [896, 896+16384) scan one adjacency
// row each into an LDS neighbor list, spill it to the global CSR arrays, and
// immediately compute pooled1[row,0:64] = sum_nbr x[j,0:64] (spmm64 fused —
// the list is already in LDS, x is L2-resident).
// ---------------------------------------------------------------------------
__global__ void fused_init_csr_kernel(
    const float* __restrict__ w00, const float* __restrict__ w01,
    const float* __restrict__ w10, const float* __restrict__ w11,
    u16* __restrict__ w00t, u16* __restrict__ w01t,
    u16* __restrict__ w10t, u16* __restrict__ w11t,
    float* __restrict__ stats,
    const float* __restrict__ adj, int* __restrict__ cnt, u16* __restrict__ cols,
    const float* __restrict__ x, u16* __restrict__ p64) {
  int b = blockIdx.x, t = threadIdx.x;
  if (b < 896) {
    if (b < 64)  { stats[b * 256 + t] = 0.f; return; }
    b -= 64;
    if (b < 64)  { w00t[(size_t)t * 64  + b] = f2bf(w00[(size_t)b * 256 + t]); return; }
    b -= 64;
    if (b < 256) { w01t[(size_t)t * 256 + b] = f2bf(w01[(size_t)b * 256 + t]); return; }
    b -= 256;
    if (b < 256) { w10t[(size_t)t * 256 + b] = f2bf(w10[(size_t)b * 256 + t]); return; }
    b -= 256;
    w11t[(size_t)t * 256 + b] = f2bf(w11[(size_t)b * 256 + t]);
    return;
  }
  const int row = b - 896;
  __shared__ int cnt_s;
  __shared__ u16 cols_s[MAXD];
  __shared__ __align__(16) float red_s[4][64];
  if (t == 0) cnt_s = 0;
  __syncthreads();
  const float* ar = adj + (size_t)row * NNODES;
#pragma unroll
  for (int p = 0; p < 16; ++p) {
    int base = (p * 256 + t) * 4;
    f32x4 v = *(const f32x4*)(ar + base);
    if (v[0] != 0.f || v[1] != 0.f || v[2] != 0.f || v[3] != 0.f) {
#pragma unroll
      for (int q = 0; q < 4; ++q)
        if (v[q] != 0.f) {
          int s = atomicAdd(&cnt_s, 1);
          if (s < MAXD) cols_s[s] = (u16)(base + q);
        }
    }
  }
  __syncthreads();
  const int n = min(cnt_s, MAXD);
  if (t == 0) cnt[row] = n;
  if (t < n) cols[(size_t)row * MAXD + t] = cols_s[t];
  // fused spmm64: 4 waves split the neighbor list, lane = column.
  const int wave = t >> 6, lane = t & 63;
  float acc = 0.f;
  for (int s = wave; s < n; s += 4) {
    int j = cols_s[s];
    acc += x[(size_t)j * 64 + lane];
  }
  red_s[wave][lane] = acc;
  __syncthreads();
  if (t < 64) {
    float v = red_s[0][t] + red_s[1][t] + red_s[2][t] + red_s[3][t];
    p64[(size_t)row * 64 + t] = f2bf(v);
  }
}

// ---------------------------------------------------------------------------
// BN finalize: fold 8 shadow partials + gamma/beta into scale/shift.
// ---------------------------------------------------------------------------
__device__ __forceinline__ void compute_bn(const float* __restrict__ stats,
                                           const float* __restrict__ gamma,
                                           const float* __restrict__ beta,
                                           float* sc_s, float* sh_s, int tid) {
  float s = 0.f, q = 0.f;
#pragma unroll
  for (int i = 0; i < 8; ++i) { s += stats[i * 512 + tid]; q += stats[i * 512 + 256 + tid]; }
  const float inv = 1.f / (float)NNODES;
  float mean = s * inv;
  float var  = q * inv - mean * mean;       // biased variance (jnp.var default)
  float rs = rsqrtf(fmaxf(var, 0.f) + BNEPS);
  float sc = gamma[tid] * rs;
  sc_s[tid] = sc;
  sh_s[tid] = beta[tid] - mean * sc;
}

// ---------------------------------------------------------------------------
// K6 (fused): pooled2[i,:] = sum_{j in nbr(i)} relu(bn(t2[j,:]))
// BN+ReLU applied per gathered element in fp32 (more accurate than the old
// bf16 h1 round-trip; removes one full kernel + 16 MB of traffic).
// ---------------------------------------------------------------------------
__global__ void spmm256_bn_kernel(const int* __restrict__ cnt, const u16* __restrict__ cols,
                                  const u16* __restrict__ T, const float* __restrict__ statsIn,
                                  const float* __restrict__ gamma, const float* __restrict__ beta,
                                  u16* __restrict__ out) {
  __shared__ __align__(16) float sc_s[256];
  __shared__ __align__(16) float sh_s[256];
  const int tid = threadIdx.x;
  compute_bn(statsIn, gamma, beta, sc_s, sh_s, tid);
  __syncthreads();
  const int wave = tid >> 6, lane = tid & 63;
  const int row = blockIdx.x * 4 + wave;
  const int n = cnt[row];
  const u16* cl = cols + (size_t)row * MAXD;
  const float sc0 = sc_s[lane * 4], sc1 = sc_s[lane * 4 + 1],
              sc2 = sc_s[lane * 4 + 2], sc3 = sc_s[lane * 4 + 3];
  const float sh0 = sh_s[lane * 4], sh1 = sh_s[lane * 4 + 1],
              sh2 = sh_s[lane * 4 + 2], sh3 = sh_s[lane * 4 + 3];
  float a0 = 0.f, a1 = 0.f, a2 = 0.f, a3 = 0.f;
  for (int s = 0; s < n; ++s) {
    int j = cl[s];
    ushort4 v = *(const ushort4*)(T + (size_t)j * 256 + lane * 4);
    a0 += fmaxf(bf2f(v.x) * sc0 + sh0, 0.f);
    a1 += fmaxf(bf2f(v.y) * sc1 + sh1, 0.f);
    a2 += fmaxf(bf2f(v.z) * sc2 + sh2, 0.f);
    a3 += fmaxf(bf2f(v.w) * sc3 + sh3, 0.f);
  }
  ushort4 o;
  o.x = f2bf(a0); o.y = f2bf(a1); o.z = f2bf(a2); o.w = f2bf(a3);
  *(ushort4*)(out + (size_t)row * 256 + lane * 4) = o;
}

// ---------------------------------------------------------------------------
// MFMA GEMM: C[16384][256] = op(A)[16384][K] @ W[K][256] + bias (bf16 in/out)
//   op(A) = relu(A*scale+shift) when BN. Emits col sum/sumsq shadows (fp32,
//   pre-rounding) for the NEXT BatchNorm.
// MFMA 16x16x32_bf16 m97-verified layout: A[m=lane&15][k=quad*8+j],
// B[k=quad*8+j][n=lane&15] (from Wt rows), D row=quad*4+reg, col=lane&15.
// ---------------------------------------------------------------------------
template <int NK, bool BN>
__global__ __launch_bounds__(256, 2) void gemm_kernel(
    const u16* __restrict__ A, const u16* __restrict__ Wt,
    const float* __restrict__ bias, const float* __restrict__ statsIn,
    const float* __restrict__ gamma, const float* __restrict__ beta,
    u16* __restrict__ C, float* __restrict__ statsOut) {
  constexpr int K = NK * 32;
  const int tid = threadIdx.x;
  const int lane = tid & 63;
  const int wave = tid >> 6;
  const int l15 = lane & 15;
  const int quad = lane >> 4;
  const int colbase = wave * 64;

  __shared__ __align__(16) float sc_s[256];
  __shared__ __align__(16) float sh_s[256];
  if constexpr (BN) {
    compute_bn(statsIn, gamma, beta, sc_s, sh_s, tid);
    __syncthreads();
  }

  FragB bfrag[NK][4];
#pragma unroll
  for (int ks = 0; ks < NK; ++ks)
#pragma unroll
    for (int ct = 0; ct < 4; ++ct) {
      int c = colbase + ct * 16 + l15;
      bfrag[ks][ct].q = *(const uint4*)(Wt + (size_t)c * K + ks * 32 + quad * 8);
    }
  float biasv[4];
#pragma unroll
  for (int ct = 0; ct < 4; ++ct) biasv[ct] = bias[colbase + ct * 16 + l15];

  float stS[4] = {0.f, 0.f, 0.f, 0.f};
  float stQ[4] = {0.f, 0.f, 0.f, 0.f};
  const f32x4 z = {0.f, 0.f, 0.f, 0.f};

  for (int rt = blockIdx.x; rt < NNODES / 16; rt += gridDim.x) {
    const u16* Arow = A + (size_t)(rt * 16 + l15) * K;
    f32x4 acc[4];
#pragma unroll
    for (int ct = 0; ct < 4; ++ct) acc[ct] = z;
#pragma unroll
    for (int ks = 0; ks < NK; ++ks) {
      FragB af;
      af.q = *(const uint4*)(Arow + ks * 32 + quad * 8);
      if constexpr (BN) {
        int kk = ks * 32 + quad * 8;
#pragma unroll
        for (int e = 0; e < 8; ++e) {
          float av = bf2f(af.us[e]);
          av = fmaxf(av * sc_s[kk + e] + sh_s[kk + e], 0.f);
          af.us[e] = f2bf(av);
        }
      }
#pragma unroll
      for (int ct = 0; ct < 4; ++ct)
        acc[ct] = __builtin_amdgcn_mfma_f32_16x16x32_bf16(af.v, bfrag[ks][ct].v, acc[ct], 0, 0, 0);
    }
#pragma unroll
    for (int ct = 0; ct < 4; ++ct) {
      int c = colbase + ct * 16 + l15;
#pragma unroll
      for (int r = 0; r < 4; ++r) {
        float v = acc[ct][r] + biasv[ct];
        C[(size_t)(rt * 16 + quad * 4 + r) * HDIM + c] = f2bf(v);
        stS[ct] += v;
        stQ[ct] += v * v;
      }
    }
  }
#pragma unroll
  for (int ct = 0; ct < 4; ++ct) {
    float v = stS[ct];
    v += __shfl_xor(v, 16);
    v += __shfl_xor(v, 32);
    float q = stQ[ct];
    q += __shfl_xor(q, 16);
    q += __shfl_xor(q, 32);
    if (quad == 0) {
      int c = colbase + ct * 16 + l15;
      float* dst = statsOut + (size_t)(blockIdx.x & 7) * 512;
      atomicAdd(dst + c, v);
      atomicAdd(dst + 256 + c, q);
    }
  }
}

// ---------------------------------------------------------------------------
// BN+ReLU apply: bf16 T in; fp32 out (h_nodes -> d_out).
// ---------------------------------------------------------------------------
template <bool F32OUT>
__global__ void bnrelu_kernel(const u16* __restrict__ T, const float* __restrict__ stats,
                              const float* __restrict__ gamma, const float* __restrict__ beta,
                              u16* __restrict__ out16, float* __restrict__ out32) {
  __shared__ __align__(16) float sc_s[256];
  __shared__ __align__(16) float sh_s[256];
  int tid = threadIdx.x;
  compute_bn(stats, gamma, beta, sc_s, sh_s, tid);
  __syncthreads();
#pragma unroll
  for (int h = 0; h < 2; ++h) {
    size_t idx = (size_t)blockIdx.x * 2048 + h * 1024 + tid * 4;
    ushort4 v = *(const ushort4*)(T + idx);
    int c = (int)(idx & 255);
    float r0 = fmaxf(bf2f(v.x) * sc_s[c]     + sh_s[c],     0.f);
    float r1 = fmaxf(bf2f(v.y) * sc_s[c + 1] + sh_s[c + 1], 0.f);
    float r2 = fmaxf(bf2f(v.z) * sc_s[c + 2] + sh_s[c + 2], 0.f);
    float r3 = fmaxf(bf2f(v.w) * sc_s[c + 3] + sh_s[c + 3], 0.f);
    if constexpr (F32OUT) {
      f32x4 o = {r0, r1, r2, r3};
      *(f32x4*)(out32 + idx) = o;
    } else {
      ushort4 o;
      o.x = f2bf(r0); o.y = f2bf(r1); o.z = f2bf(r2); o.w = f2bf(r3);
      *(ushort4*)(out16 + idx) = o;
    }
  }
}

// ---------------------------------------------------------------------------
// Readout: part[chunk, g, h] = sum_{j in chunk} gp[g,j]*h2[j,h]   (h2 fp32)
// grid = 8 graph-groups x 64 node-chunks(256); block 256 (thread = column).
// ---------------------------------------------------------------------------
__global__ void pool_kernel(const float* __restrict__ gp, const float* __restrict__ h2,
                            float* __restrict__ part) {
  int gg = blockIdx.x >> 6, chunk = blockIdx.x & 63;
  int col = threadIdx.x;
  __shared__ __align__(16) float gpsT[256][20];
#pragma unroll
  for (int g = 0; g < 16; ++g)
    gpsT[col][g] = gp[(size_t)(gg * 16 + g) * NNODES + chunk * 256 + col];
  __syncthreads();
  float acc[16];
#pragma unroll
  for (int g = 0; g < 16; ++g) acc[g] = 0.f;
  for (int j = 0; j < 256; ++j) {
    float hv = h2[(size_t)(chunk * 256 + j) * 256 + col];
    const float* gb = &gpsT[j][0];
    f32x4 r0 = *(const f32x4*)(gb);
    f32x4 r1 = *(const f32x4*)(gb + 4);
    f32x4 r2 = *(const f32x4*)(gb + 8);
    f32x4 r3 = *(const f32x4*)(gb + 12);
#pragma unroll
    for (int g = 0; g < 4; ++g) {
      acc[g]      += r0[g] * hv;
      acc[4 + g]  += r1[g] * hv;
      acc[8 + g]  += r2[g] * hv;
      acc[12 + g] += r3[g] * hv;
    }
  }
#pragma unroll
  for (int g = 0; g < 16; ++g)
    part[(size_t)chunk * 32768 + (size_t)(gg * 16 + g) * 256 + col] = acc[g];
}

__global__ void poolfin_kernel(const float* __restrict__ part, float* __restrict__ out0) {
  int g = blockIdx.x, col = threadIdx.x;
  float s = 0.f;
#pragma unroll 8
  for (int c = 0; c < 64; ++c) s += part[(size_t)c * 32768 + (size_t)g * 256 + col];
  out0[(size_t)g * 256 + col] = s;
}

// ---------------------------------------------------------------------------
extern "C" void kernel_launch(void* const* d_in, const int* in_sizes, int n_in,
                              void* d_out, int out_size, void* d_ws, size_t ws_size,
                              hipStream_t stream) {
  (void)in_sizes; (void)n_in; (void)out_size; (void)ws_size;
  const float* x    = (const float*)d_in[0];
  const float* adj  = (const float*)d_in[1];
  const float* gp   = (const float*)d_in[2];
  const float* w00  = (const float*)d_in[3];
  const float* b00  = (const float*)d_in[4];
  const float* g00  = (const float*)d_in[5];
  const float* be00 = (const float*)d_in[6];
  const float* w01  = (const float*)d_in[7];
  const float* b01  = (const float*)d_in[8];
  const float* g0   = (const float*)d_in[9];
  const float* be0  = (const float*)d_in[10];
  const float* w10  = (const float*)d_in[11];
  const float* b10  = (const float*)d_in[12];
  const float* g10  = (const float*)d_in[13];
  const float* be10 = (const float*)d_in[14];
  const float* w11  = (const float*)d_in[15];
  const float* b11  = (const float*)d_in[16];
  const float* g1   = (const float*)d_in[17];
  const float* be1  = (const float*)d_in[18];

  // Workspace map — 22.5 MB total.
  char* ws = (char*)d_ws;
  u16*   colidx = (u16*)(ws + 0);               // 4,194,304  [16384][128] u16
  int*   cnt    = (int*)(ws + 4194304);         //    65,536
  u16*   w00t   = (u16*)(ws + 4259840);         //    32,768  [256][64]
  u16*   w01t   = (u16*)(ws + 4292608);         //   131,072  [256][256]
  u16*   w10t   = (u16*)(ws + 4423680);         //   131,072
  u16*   w11t   = (u16*)(ws + 4554752);         //   131,072
  float* stats  = (float*)(ws + 4685824);       //    65,536  4 bufs x 8 x 512
  u16*   P64    = (u16*)(ws + 4751360);         // 2,097,152  [16384][64] bf16
  u16*   T0     = (u16*)(ws + 6848512);         // 8,388,608  [16384][256] bf16
  u16*   T1     = (u16*)(ws + 15237120);        // 8,388,608  -> ends 23,625,728
  float* part   = (float*)T1;                   // 8 MB fp32, aliases dead t3

  // d_out is FP32 (reference output dtype): pooled [128][256] then h_nodes.
  float* out_pool  = (float*)d_out;
  float* out_nodes = out_pool + 32768;

  // init + csr-build + spmm64, one kernel.
  fused_init_csr_kernel<<<896 + NNODES, 256, 0, stream>>>(
      w00, w01, w10, w11, w00t, w01t, w10t, w11t, stats,
      adj, cnt, colidx, x, P64);
  // layer 1: t1 = pooled1@w00 ; t2 = relu(bn(t1))@w01
  gemm_kernel<2, false><<<512, 256, 0, stream>>>(P64, w00t, b00, nullptr, nullptr, nullptr,
                                                 T0, stats + 0);
  gemm_kernel<8, true><<<512, 256, 0, stream>>>(T0, w01t, b01, stats + 0, g00, be00,
                                                T1, stats + 4096);
  // layer 2: pooled2 = adj @ relu(bn(t2)) with BN fused into the gather.
  spmm256_bn_kernel<<<NNODES / 4, 256, 0, stream>>>(cnt, colidx, T1, stats + 4096, g0, be0,
                                                    T0);                     // pooled2 -> T0
  gemm_kernel<8, false><<<512, 256, 0, stream>>>(T0, w10t, b10, nullptr, nullptr, nullptr,
                                                 T1, stats + 8192);          // t3 -> T1
  gemm_kernel<8, true><<<512, 256, 0, stream>>>(T1, w11t, b11, stats + 8192, g10, be10,
                                                T0, stats + 12288);          // t4 -> T0
  bnrelu_kernel<true><<<2048, 256, 0, stream>>>(T0, stats + 12288, g1, be1,
                                                nullptr, out_nodes);         // h2 -> d_out (fp32)
  // readout
  pool_kernel<<<512, 256, 0, stream>>>(gp, out_nodes, part);
  poolfin_kernel<<<128, 256, 0, stream>>>(part, out_pool);
}